// Round 2
// baseline (22250.784 us; speedup 1.0000x reference)
//
#include <hip/hip_runtime.h>
#include <math.h>

#define B_   32
#define L_   512
#define E_   300
#define H_   256
#define T_   4
#define G4H  1024   // 4*H
#define NTOK 16384  // B*L
#define XGLD 2048   // 2 directions * 4H

__device__ __forceinline__ float sigmoidf_(float x) { return 1.0f / (1.0f + expf(-x)); }

// ---------- transpose Whh [1024][256] -> WhhT [256][1024] ----------
__global__ __launch_bounds__(256) void transpose_k(const float* __restrict__ src,
                                                   float* __restrict__ dst) {
  __shared__ float tile[32][33];
  int lx = threadIdx.x & 31;
  int ly = threadIdx.x >> 5;            // 0..7
  int c0 = blockIdx.x * 32;             // k tile
  int r0 = blockIdx.y * 32;             // g tile
#pragma unroll
  for (int i = 0; i < 32; i += 8)
    tile[ly + i][lx] = src[(size_t)(r0 + ly + i) * H_ + c0 + lx];
  __syncthreads();
#pragma unroll
  for (int i = 0; i < 32; i += 8)
    dst[(size_t)(c0 + ly + i) * G4H + r0 + lx] = tile[lx][ly + i];
}

// ---------- stage A: xg[row][d*1024+g] = emb[wid[row]] . Wih_d[g] + b_d[g] ----------
#define BM 64
#define BN 64
#define BK 20
__global__ __launch_bounds__(256) void xproj_kernel(
    const int*   __restrict__ wid,    // [NTOK]
    const float* __restrict__ emb,    // [V][300]
    const float* __restrict__ wih_f,  // [1024][300]
    const float* __restrict__ wih_b,
    const float* __restrict__ b_f,
    const float* __restrict__ b_b,
    float* __restrict__ xg)           // [NTOK][2048]
{
  __shared__ float As[BM][BK + 1];
  __shared__ float Bs[BK][BN];
  __shared__ int   wid_s[BM];

  int tid = threadIdx.x;
  int m0 = blockIdx.y * BM;
  int n0 = blockIdx.x * BN;            // global col 0..2047
  int d  = n0 >> 10;
  const float* wih  = d ? wih_b : wih_f;
  const float* bias = d ? b_b  : b_f;
  int g0 = n0 & 1023;

  if (tid < BM) wid_s[tid] = wid[m0 + tid];
  __syncthreads();

  int lm = tid >> 2;          // 0..63
  int lk = (tid & 3) * 5;     // 0,5,10,15
  int tx = tid & 15, ty = tid >> 4;

  float acc[4][4] = {};

  for (int k0 = 0; k0 < 300; k0 += BK) {
    const float* erow = emb + (size_t)wid_s[lm] * E_ + k0 + lk;
#pragma unroll
    for (int i = 0; i < 5; ++i) As[lm][lk + i] = erow[i];
    const float* wrow = wih + (size_t)(g0 + lm) * E_ + k0 + lk;
#pragma unroll
    for (int i = 0; i < 5; ++i) Bs[lk + i][lm] = wrow[i];
    __syncthreads();
#pragma unroll
    for (int k = 0; k < BK; ++k) {
      float a0 = As[ty * 4 + 0][k], a1 = As[ty * 4 + 1][k];
      float a2 = As[ty * 4 + 2][k], a3 = As[ty * 4 + 3][k];
      float b0 = Bs[k][tx * 4 + 0], b1 = Bs[k][tx * 4 + 1];
      float b2 = Bs[k][tx * 4 + 2], b3 = Bs[k][tx * 4 + 3];
      acc[0][0] += a0 * b0; acc[0][1] += a0 * b1; acc[0][2] += a0 * b2; acc[0][3] += a0 * b3;
      acc[1][0] += a1 * b0; acc[1][1] += a1 * b1; acc[1][2] += a1 * b2; acc[1][3] += a1 * b3;
      acc[2][0] += a2 * b0; acc[2][1] += a2 * b1; acc[2][2] += a2 * b2; acc[2][3] += a2 * b3;
      acc[3][0] += a3 * b0; acc[3][1] += a3 * b1; acc[3][2] += a3 * b2; acc[3][3] += a3 * b3;
    }
    __syncthreads();
  }

#pragma unroll
  for (int i = 0; i < 4; ++i) {
    int row = m0 + ty * 4 + i;
    float* op = xg + (size_t)row * XGLD + n0 + tx * 4;
#pragma unroll
    for (int jj = 0; jj < 4; ++jj)
      op[jj] = acc[i][jj] + bias[g0 + tx * 4 + jj];
  }
}

// ---------- stage B: LSTM recurrence, weights resident in VGPRs ----------
// one block per (dir, batch); 1024 threads; thread g owns gate-output g.
// Each thread keeps WhhT[:, g] (256 fp32) in registers, loaded once.
__global__ __launch_bounds__(1024, 4) void lstm_kernel(
    const float* __restrict__ xg,    // [NTOK][2048]
    const float* __restrict__ whhT,  // [2][256][1024]  (k-major)
    const float* __restrict__ wout,  // [4][512]
    float* __restrict__ em)          // [2][32][512][4]
{
  int blk = blockIdx.x;              // 0..63
  int d = blk >> 5;
  int b = blk & 31;
  int g = threadIdx.x;               // gate index 0..1023
  int gtype = g >> 8;                // 0=i, 1=f, 2=g(tanh), 3=o

  const float* WT = whhT + (size_t)d * (H_ * G4H);

  // ---- load this thread's weight column into registers (once) ----
  float w[H_];
#pragma unroll
  for (int k = 0; k < H_; ++k)
    w[k] = WT[(size_t)k * G4H + g];

  __shared__ float h_lds[H_];
  __shared__ float gate_lds[G4H];

  int wave = g >> 6, lane = g & 63;
  float wo[4];
  if (g < 256) {
#pragma unroll
    for (int cc = 0; cc < 4; ++cc)
      wo[cc] = wout[wave * 512 + d * 256 + cc * 64 + lane];
  }

  float c = 0.0f;
  if (g < H_) h_lds[g] = 0.0f;
  __syncthreads();

  for (int s = 0; s < L_; ++s) {
    int t = d ? (L_ - 1 - s) : s;
    // per-thread x-gate preactivation (coalesced, streams xg once total)
    float acc = xg[((size_t)(b * L_ + t)) * XGLD + d * G4H + g];

    // h (previous step) broadcast from LDS; weights from registers
#pragma unroll
    for (int k4 = 0; k4 < H_ / 4; ++k4) {
      float4 h4 = *(const float4*)&h_lds[k4 * 4];
      acc += h4.x * w[k4 * 4 + 0];
      acc += h4.y * w[k4 * 4 + 1];
      acc += h4.z * w[k4 * 4 + 2];
      acc += h4.w * w[k4 * 4 + 3];
    }

    float act = (gtype == 2) ? tanhf(acc) : sigmoidf_(acc);
    gate_lds[g] = act;
    __syncthreads();   // gates complete; also: all reads of previous h done

    if (g < H_) {
      float ig = gate_lds[g];
      float fg = gate_lds[H_ + g];
      float gg = gate_lds[2 * H_ + g];
      float og = gate_lds[3 * H_ + g];
      c = fg * c + ig * gg;
      h_lds[g] = og * tanhf(c);
    }
    __syncthreads();   // h complete for emissions + next step

    // emissions: waves 0..3 compute tag=wave for this direction
    if (g < 256) {
      float part = 0.0f;
#pragma unroll
      for (int cc = 0; cc < 4; ++cc)
        part += h_lds[cc * 64 + lane] * wo[cc];
#pragma unroll
      for (int off = 32; off >= 1; off >>= 1)
        part += __shfl_down(part, off, 64);
      if (lane == 0)
        em[(((size_t)(d * 32 + b)) * L_ + t) * 4 + wave] = part;
    }
  }
}

// ---------- Viterbi decode ----------
__global__ __launch_bounds__(64) void viterbi_kernel(
    const float* __restrict__ em,      // [2][32][512][4]
    const float* __restrict__ bout,    // [4]
    const float* __restrict__ trans,   // [4][4]
    const float* __restrict__ strans,  // [4]
    const float* __restrict__ etrans,  // [4]
    const int*   __restrict__ mask,    // [32][512]
    int* __restrict__ hist,            // [32][512][4]
    int* __restrict__ out)             // [32][512]
{
  int b = threadIdx.x;
  if (b >= B_) return;

  const float* emf = em + ((size_t)b * L_) * 4;
  const float* emb2 = em + ((size_t)(B_ + b) * L_) * 4;

  float tr[4][4];
#pragma unroll
  for (int i = 0; i < 4; ++i)
#pragma unroll
    for (int jj = 0; jj < 4; ++jj) tr[i][jj] = trans[i * 4 + jj];
  float bo[4];
#pragma unroll
  for (int i = 0; i < 4; ++i) bo[i] = bout[i];

  float sc[4];
#pragma unroll
  for (int tag = 0; tag < 4; ++tag)
    sc[tag] = strans[tag] + emf[0 * 4 + tag] + emb2[0 * 4 + tag] + bo[tag];

  for (int t = 1; t < L_; ++t) {
    float ns[4];
#pragma unroll
    for (int to = 0; to < 4; ++to) {
      float best = sc[0] + tr[0][to];
      int bf = 0;
#pragma unroll
      for (int fr = 1; fr < 4; ++fr) {
        float v = sc[fr] + tr[fr][to];
        if (v > best) { best = v; bf = fr; }
      }
      ns[to] = best + emf[t * 4 + to] + emb2[t * 4 + to] + bo[to];
      hist[((size_t)b * L_ + t) * 4 + to] = bf;
    }
    int mt = mask[b * L_ + t];
#pragma unroll
    for (int to = 0; to < 4; ++to) sc[to] = mt ? ns[to] : sc[to];
  }

#pragma unroll
  for (int tag = 0; tag < 4; ++tag) sc[tag] += etrans[tag];
  int cur = 0;
  float best = sc[0];
#pragma unroll
  for (int i = 1; i < 4; ++i)
    if (sc[i] > best) { best = sc[i]; cur = i; }

  out[b * L_ + (L_ - 1)] = cur * (mask[b * L_ + (L_ - 1)] ? 1 : 0);
  for (int t = L_ - 1; t >= 1; --t) {
    if (mask[b * L_ + t]) cur = hist[((size_t)b * L_ + t) * 4 + cur];
    out[b * L_ + (t - 1)] = cur * (mask[b * L_ + (t - 1)] ? 1 : 0);
  }
}

extern "C" void kernel_launch(void* const* d_in, const int* in_sizes, int n_in,
                              void* d_out, int out_size, void* d_ws, size_t ws_size,
                              hipStream_t stream) {
  const int*   word_ids = (const int*)d_in[0];
  const int*   mask     = (const int*)d_in[1];
  // d_in[2] label_ids: unused
  const float* emb   = (const float*)d_in[3];
  const float* Wih_f = (const float*)d_in[4];
  const float* Whh_f = (const float*)d_in[5];
  const float* b_f   = (const float*)d_in[6];
  const float* Wih_b = (const float*)d_in[7];
  const float* Whh_b = (const float*)d_in[8];
  const float* b_b   = (const float*)d_in[9];
  const float* W_out = (const float*)d_in[10];
  const float* b_out = (const float*)d_in[11];
  const float* trans = (const float*)d_in[12];
  const float* strans = (const float*)d_in[13];
  const float* etrans = (const float*)d_in[14];
  int* out = (int*)d_out;

  float* xg   = (float*)d_ws;                         // 16384*2048 f32 = 128 MiB
  float* whhT = xg + (size_t)NTOK * XGLD;             // 2*256*1024 f32 = 2 MiB
  float* em   = whhT + (size_t)2 * H_ * G4H;          // 2*32*512*4 f32 = 0.5 MiB
  int*   hist = (int*)(em + (size_t)2 * B_ * L_ * T_);// 32*512*4 i32 = 0.25 MiB

  transpose_k<<<dim3(8, 32), 256, 0, stream>>>(Whh_f, whhT);
  transpose_k<<<dim3(8, 32), 256, 0, stream>>>(Whh_b, whhT + (size_t)H_ * G4H);
  xproj_kernel<<<dim3(32, 256), 256, 0, stream>>>(word_ids, emb, Wih_f, Wih_b, b_f, b_b, xg);
  lstm_kernel<<<64, 1024, 0, stream>>>(xg, whhT, W_out, em);
  viterbi_kernel<<<1, 64, 0, stream>>>(em, b_out, trans, strans, etrans, mask, hist, out);
}

// Round 3
// 21558.656 us; speedup vs baseline: 1.0321x; 1.0321x over previous
//
#include <hip/hip_runtime.h>
#include <math.h>

#define B_   32
#define L_   512
#define E_   300
#define H_   256
#define T_   4
#define NTOK 16384  // B*L
#define XGLD 2048   // 2 directions * 4H

__device__ __forceinline__ float sigmoidf_(float x) { return 1.0f / (1.0f + expf(-x)); }

// ---------- stage A: xg[row][d*1024+g] = emb[wid[row]] . Wih_d[g] + b_d[g] ----------
#define BM 64
#define BN 64
#define BK 20
__global__ __launch_bounds__(256) void xproj_kernel(
    const int*   __restrict__ wid,    // [NTOK]
    const float* __restrict__ emb,    // [V][300]
    const float* __restrict__ wih_f,  // [1024][300]
    const float* __restrict__ wih_b,
    const float* __restrict__ b_f,
    const float* __restrict__ b_b,
    float* __restrict__ xg)           // [NTOK][2048]
{
  __shared__ float As[BM][BK + 1];
  __shared__ float Bs[BK][BN];
  __shared__ int   wid_s[BM];

  int tid = threadIdx.x;
  int m0 = blockIdx.y * BM;
  int n0 = blockIdx.x * BN;            // global col 0..2047
  int d  = n0 >> 10;
  const float* wih  = d ? wih_b : wih_f;
  const float* bias = d ? b_b  : b_f;
  int g0 = n0 & 1023;

  if (tid < BM) wid_s[tid] = wid[m0 + tid];
  __syncthreads();

  int lm = tid >> 2;          // 0..63
  int lk = (tid & 3) * 5;     // 0,5,10,15
  int tx = tid & 15, ty = tid >> 4;

  float acc[4][4] = {};

  for (int k0 = 0; k0 < 300; k0 += BK) {
    const float* erow = emb + (size_t)wid_s[lm] * E_ + k0 + lk;
#pragma unroll
    for (int i = 0; i < 5; ++i) As[lm][lk + i] = erow[i];
    const float* wrow = wih + (size_t)(g0 + lm) * E_ + k0 + lk;
#pragma unroll
    for (int i = 0; i < 5; ++i) Bs[lk + i][lm] = wrow[i];
    __syncthreads();
#pragma unroll
    for (int k = 0; k < BK; ++k) {
      float a0 = As[ty * 4 + 0][k], a1 = As[ty * 4 + 1][k];
      float a2 = As[ty * 4 + 2][k], a3 = As[ty * 4 + 3][k];
      float b0 = Bs[k][tx * 4 + 0], b1 = Bs[k][tx * 4 + 1];
      float b2 = Bs[k][tx * 4 + 2], b3 = Bs[k][tx * 4 + 3];
      acc[0][0] += a0 * b0; acc[0][1] += a0 * b1; acc[0][2] += a0 * b2; acc[0][3] += a0 * b3;
      acc[1][0] += a1 * b0; acc[1][1] += a1 * b1; acc[1][2] += a1 * b2; acc[1][3] += a1 * b3;
      acc[2][0] += a2 * b0; acc[2][1] += a2 * b1; acc[2][2] += a2 * b2; acc[2][3] += a2 * b3;
      acc[3][0] += a3 * b0; acc[3][1] += a3 * b1; acc[3][2] += a3 * b2; acc[3][3] += a3 * b3;
    }
    __syncthreads();
  }

#pragma unroll
  for (int i = 0; i < 4; ++i) {
    int row = m0 + ty * 4 + i;
    float* op = xg + (size_t)row * XGLD + n0 + tx * 4;
#pragma unroll
    for (int jj = 0; jj < 4; ++jj)
      op[jj] = acc[i][jj] + bias[g0 + tx * 4 + jj];
  }
}

// ---------- flag init (replay-safe zeroing each launch) ----------
__global__ __launch_bounds__(256) void init_flags(int* flags) { flags[threadIdx.x] = 0; }

// ---------- stage B: LSTM, 4 blocks per (dir,batch), weights in VGPRs ----------
// block = group(64) x q(4). Block owns hidden slice j in [q*64, q*64+64) and its
// 4 gate rows (256 outputs). 512 threads: p = output index (gt*64+jj), khalf = k half.
// Each thread holds 128 Whh weights in registers. Per step the 4 blocks exchange
// their 64-float h-slices through global memory with agent-scope flag sync.
__global__ __launch_bounds__(512, 2) void lstm_kernel(
    const float* __restrict__ xg,     // [NTOK][2048]
    const float* __restrict__ whh_f,  // [1024][256]
    const float* __restrict__ whh_b,  // [1024][256]
    const float* __restrict__ wout,   // [4][512]
    float*       h_ex,                // [64][2][256]   (group, slot, j)
    int*         flags,               // [64][4]
    float* __restrict__ em_part)      // [64][512][4][4] (grp, t, q, tag)
{
  const int blk = blockIdx.x;
  const int grp = blk & 63;          // (d,b): consecutive ids -> same-XCD partners
  const int q   = blk >> 6;          // 0..3
  const int d = grp >> 5, b = grp & 31;
  const int tid = threadIdx.x;
  const int p = tid & 255;           // output index within block
  const int khalf = tid >> 8;        // 0/1 (wave-uniform)
  const int gt = p >> 6;             // gate type 0=i,1=f,2=g,3=o
  const int jj = p & 63;
  const int grow = gt * 256 + q * 64 + jj;   // row in Whh [0,1024)
  const float* __restrict__ whh = d ? whh_b : whh_f;

  // weights: Whh[grow][khalf*128 .. +128) -> 128 VGPRs (static unroll)
  float w[128];
  {
    const float4* wp = (const float4*)(whh + (size_t)grow * H_ + khalf * 128);
#pragma unroll
    for (int i = 0; i < 32; ++i) {
      float4 v = wp[i];
      w[4 * i + 0] = v.x; w[4 * i + 1] = v.y; w[4 * i + 2] = v.z; w[4 * i + 3] = v.w;
    }
  }

  __shared__ float h_cur[H_];        // full h vector (input to current step)
  __shared__ float part[2][256];     // k-half partials

  float wo0 = 0.f, wo1 = 0.f, wo2 = 0.f, wo3 = 0.f;
  if (tid < 64) {
    wo0 = wout[0 * 512 + d * 256 + q * 64 + tid];
    wo1 = wout[1 * 512 + d * 256 + q * 64 + tid];
    wo2 = wout[2 * 512 + d * 256 + q * 64 + tid];
    wo3 = wout[3 * 512 + d * 256 + q * 64 + tid];
  }

  if (tid < 256) h_cur[tid] = 0.f;
  float c = 0.f;
  __syncthreads();

  int*   flg  = flags + grp * 4;
  float* hex0 = h_ex + (size_t)grp * 512;   // [2][256]

  for (int s = 0; s < L_; ++s) {
    const int t = d ? (L_ - 1 - s) : s;

    float acc = (khalf == 0)
        ? xg[((size_t)(b * L_ + t)) * XGLD + d * 1024 + grow]
        : 0.f;
    const float* hb = h_cur + khalf * 128;
#pragma unroll
    for (int k = 0; k < 32; ++k) {
      float4 h4 = *(const float4*)(hb + 4 * k);   // broadcast: wave-uniform address
      acc += h4.x * w[4 * k + 0] + h4.y * w[4 * k + 1]
           + h4.z * w[4 * k + 2] + h4.w * w[4 * k + 3];
    }
    part[khalf][p] = acc;
    __syncthreads();

    if (tid < 64) {
      float gi = part[0][tid]       + part[1][tid];
      float gf = part[0][64 + tid]  + part[1][64 + tid];
      float gg = part[0][128 + tid] + part[1][128 + tid];
      float go = part[0][192 + tid] + part[1][192 + tid];
      gi = sigmoidf_(gi); gf = sigmoidf_(gf);
      gg = tanhf(gg);     go = sigmoidf_(go);
      c = gf * c + gi * gg;
      float h = go * tanhf(c);
      hex0[(s & 1) * 256 + q * 64 + tid] = h;

      // per-slice emission partials (4 tags), butterfly reduce over 64 lanes
      float r0 = h * wo0, r1 = h * wo1, r2 = h * wo2, r3 = h * wo3;
#pragma unroll
      for (int m = 1; m < 64; m <<= 1) {
        r0 += __shfl_xor(r0, m, 64);
        r1 += __shfl_xor(r1, m, 64);
        r2 += __shfl_xor(r2, m, 64);
        r3 += __shfl_xor(r3, m, 64);
      }
      if (tid == 0) {
        float* ep = em_part + (((size_t)grp * L_ + t) * 4 + q) * 4;
        ep[0] = r0; ep[1] = r1; ep[2] = r2; ep[3] = r3;
      }
      __threadfence();   // drain h/em stores to device scope before flag
      if (tid == 0)
        __hip_atomic_store(&flg[q], s + 1, __ATOMIC_RELAXED, __HIP_MEMORY_SCOPE_AGENT);
    }

    if (s == L_ - 1) break;

    // wait for the 3 partner slices of this step
    const int target = s + 1;
#pragma unroll
    for (int qq = 0; qq < 4; ++qq) {
      if (qq == q) continue;
      while (__hip_atomic_load(&flg[qq], __ATOMIC_RELAXED, __HIP_MEMORY_SCOPE_AGENT) < target) {}
    }
    __threadfence();   // acquire: invalidate caches before reading partner h
    __syncthreads();
    if (tid < 256) h_cur[tid] = hex0[(s & 1) * 256 + tid];
    __syncthreads();
  }
}

// ---------- emission sum: em[b][t][tag] = b_out + sum over (d,q) partials ----------
__global__ __launch_bounds__(256) void emsum_kernel(
    const float* __restrict__ em_part,  // [2][32][512][4][4]
    const float* __restrict__ bout,     // [4]
    float* __restrict__ em)             // [32][512][4]
{
  int idx = blockIdx.x * 256 + threadIdx.x;    // over 32*512*4
  if (idx >= B_ * L_ * T_) return;
  int tag = idx & 3;
  int bt  = idx >> 2;                           // b*512 + t
  float v = bout[tag];
#pragma unroll
  for (int dd = 0; dd < 2; ++dd)
#pragma unroll
    for (int qq = 0; qq < 4; ++qq)
      v += em_part[((size_t)(dd * B_ * L_) + bt) * 16 + qq * 4 + tag];
  em[idx] = v;
}

// ---------- Viterbi decode ----------
__global__ __launch_bounds__(64) void viterbi_kernel(
    const float* __restrict__ em,      // [32][512][4]  (bias + both dirs included)
    const float* __restrict__ trans,   // [4][4]
    const float* __restrict__ strans,  // [4]
    const float* __restrict__ etrans,  // [4]
    const int*   __restrict__ mask,    // [32][512]
    int* __restrict__ hist,            // [32][512][4]
    int* __restrict__ out)             // [32][512]
{
  int b = threadIdx.x;
  if (b >= B_) return;

  const float* emb2 = em + (size_t)b * L_ * 4;

  float tr[4][4];
#pragma unroll
  for (int i = 0; i < 4; ++i)
#pragma unroll
    for (int jj = 0; jj < 4; ++jj) tr[i][jj] = trans[i * 4 + jj];

  float sc[4];
#pragma unroll
  for (int tag = 0; tag < 4; ++tag)
    sc[tag] = strans[tag] + emb2[tag];

  for (int t = 1; t < L_; ++t) {
    float ns[4];
#pragma unroll
    for (int to = 0; to < 4; ++to) {
      float best = sc[0] + tr[0][to];
      int bf = 0;
#pragma unroll
      for (int fr = 1; fr < 4; ++fr) {
        float v = sc[fr] + tr[fr][to];
        if (v > best) { best = v; bf = fr; }
      }
      ns[to] = best + emb2[t * 4 + to];
      hist[((size_t)b * L_ + t) * 4 + to] = bf;
    }
    int mt = mask[b * L_ + t];
#pragma unroll
    for (int to = 0; to < 4; ++to) sc[to] = mt ? ns[to] : sc[to];
  }

#pragma unroll
  for (int tag = 0; tag < 4; ++tag) sc[tag] += etrans[tag];
  int cur = 0;
  float best = sc[0];
#pragma unroll
  for (int i = 1; i < 4; ++i)
    if (sc[i] > best) { best = sc[i]; cur = i; }

  out[b * L_ + (L_ - 1)] = cur * (mask[b * L_ + (L_ - 1)] ? 1 : 0);
  for (int t = L_ - 1; t >= 1; --t) {
    if (mask[b * L_ + t]) cur = hist[((size_t)b * L_ + t) * 4 + cur];
    out[b * L_ + (t - 1)] = cur * (mask[b * L_ + (t - 1)] ? 1 : 0);
  }
}

extern "C" void kernel_launch(void* const* d_in, const int* in_sizes, int n_in,
                              void* d_out, int out_size, void* d_ws, size_t ws_size,
                              hipStream_t stream) {
  const int*   word_ids = (const int*)d_in[0];
  const int*   mask     = (const int*)d_in[1];
  // d_in[2] label_ids: unused
  const float* emb   = (const float*)d_in[3];
  const float* Wih_f = (const float*)d_in[4];
  const float* Whh_f = (const float*)d_in[5];
  const float* b_f   = (const float*)d_in[6];
  const float* Wih_b = (const float*)d_in[7];
  const float* Whh_b = (const float*)d_in[8];
  const float* b_b   = (const float*)d_in[9];
  const float* W_out = (const float*)d_in[10];
  const float* b_out = (const float*)d_in[11];
  const float* trans = (const float*)d_in[12];
  const float* strans = (const float*)d_in[13];
  const float* etrans = (const float*)d_in[14];
  int* out = (int*)d_out;

  float* xg      = (float*)d_ws;                          // 128 MiB
  float* em_part = xg + (size_t)NTOK * XGLD;              // 2 MiB
  float* h_ex    = em_part + (size_t)64 * L_ * 16;        // 128 KiB
  int*   flags   = (int*)(h_ex + 64 * 2 * 256);           // 1 KiB
  float* em      = (float*)(flags + 256);                 // 256 KiB
  int*   hist    = (int*)(em + (size_t)B_ * L_ * T_);     // 256 KiB

  init_flags<<<1, 256, 0, stream>>>(flags);
  xproj_kernel<<<dim3(32, 256), 256, 0, stream>>>(word_ids, emb, Wih_f, Wih_b, b_f, b_b, xg);
  lstm_kernel<<<256, 512, 0, stream>>>(xg, Whh_f, Whh_b, W_out, h_ex, flags, em_part);
  emsum_kernel<<<256, 256, 0, stream>>>(em_part, b_out, em);
  viterbi_kernel<<<1, 64, 0, stream>>>(em, trans, strans, etrans, mask, hist, out);
}

// Round 4
// 3804.076 us; speedup vs baseline: 5.8492x; 5.6673x over previous
//
#include <hip/hip_runtime.h>
#include <math.h>

#define B_   32
#define L_   512
#define E_   300
#define H_   256
#define T_   4
#define NTOK 16384  // B*L
#define XGLD 2048   // 2 directions * 4H

__device__ __forceinline__ float sigmoidf_(float x) { return 1.0f / (1.0f + expf(-x)); }

// ---------- stage A: xg[row][d*1024+g] = emb[wid[row]] . Wih_d[g] + b_d[g] ----------
#define BM 64
#define BN 64
#define BK 20
__global__ __launch_bounds__(256) void xproj_kernel(
    const int*   __restrict__ wid,    // [NTOK]
    const float* __restrict__ emb,    // [V][300]
    const float* __restrict__ wih_f,  // [1024][300]
    const float* __restrict__ wih_b,
    const float* __restrict__ b_f,
    const float* __restrict__ b_b,
    float* __restrict__ xg)           // [NTOK][2048]
{
  __shared__ float As[BM][BK + 1];
  __shared__ float Bs[BK][BN];
  __shared__ int   wid_s[BM];

  int tid = threadIdx.x;
  int m0 = blockIdx.y * BM;
  int n0 = blockIdx.x * BN;            // global col 0..2047
  int d  = n0 >> 10;
  const float* wih  = d ? wih_b : wih_f;
  const float* bias = d ? b_b  : b_f;
  int g0 = n0 & 1023;

  if (tid < BM) wid_s[tid] = wid[m0 + tid];
  __syncthreads();

  int lm = tid >> 2;          // 0..63
  int lk = (tid & 3) * 5;     // 0,5,10,15
  int tx = tid & 15, ty = tid >> 4;

  float acc[4][4] = {};

  for (int k0 = 0; k0 < 300; k0 += BK) {
    const float* erow = emb + (size_t)wid_s[lm] * E_ + k0 + lk;
#pragma unroll
    for (int i = 0; i < 5; ++i) As[lm][lk + i] = erow[i];
    const float* wrow = wih + (size_t)(g0 + lm) * E_ + k0 + lk;
#pragma unroll
    for (int i = 0; i < 5; ++i) Bs[lk + i][lm] = wrow[i];
    __syncthreads();
#pragma unroll
    for (int k = 0; k < BK; ++k) {
      float a0 = As[ty * 4 + 0][k], a1 = As[ty * 4 + 1][k];
      float a2 = As[ty * 4 + 2][k], a3 = As[ty * 4 + 3][k];
      float b0 = Bs[k][tx * 4 + 0], b1 = Bs[k][tx * 4 + 1];
      float b2 = Bs[k][tx * 4 + 2], b3 = Bs[k][tx * 4 + 3];
      acc[0][0] += a0 * b0; acc[0][1] += a0 * b1; acc[0][2] += a0 * b2; acc[0][3] += a0 * b3;
      acc[1][0] += a1 * b0; acc[1][1] += a1 * b1; acc[1][2] += a1 * b2; acc[1][3] += a1 * b3;
      acc[2][0] += a2 * b0; acc[2][1] += a2 * b1; acc[2][2] += a2 * b2; acc[2][3] += a2 * b3;
      acc[3][0] += a3 * b0; acc[3][1] += a3 * b1; acc[3][2] += a3 * b2; acc[3][3] += a3 * b3;
    }
    __syncthreads();
  }

#pragma unroll
  for (int i = 0; i < 4; ++i) {
    int row = m0 + ty * 4 + i;
    float* op = xg + (size_t)row * XGLD + n0 + tx * 4;
#pragma unroll
    for (int jj = 0; jj < 4; ++jj)
      op[jj] = acc[i][jj] + bias[g0 + tx * 4 + jj];
  }
}

// ---------- flag init (replay-safe zeroing each launch) ----------
__global__ __launch_bounds__(128) void init_flags(int* flags) { flags[threadIdx.x] = 0; }

// ---------- stage B: LSTM, LDS-resident weight slices + LLC relaxed-atomic h exchange ----
// Block = (d, slice sl of 8 hidden units, batch-half bh of 16 batches).
// 512 threads: tid = gl*16 + bl; gl in [0,32) = 4 gates x 8 units; bl in [0,16).
// Whh slice (32 rows x 256) lives in LDS. h exchanged through h_all (LLC) with
// relaxed agent-scope atomics + per-slice step flags. No fences.
__global__ __launch_bounds__(512) void lstm_kernel(
    const float* __restrict__ xg,     // [NTOK][2048]
    const float* __restrict__ whh_f,  // [1024][256]
    const float* __restrict__ whh_b,  // [1024][256]
    float*       h_all,               // [2][2][512][16][256]  (d, bh, t, bl, j)
    int*         flags)               // [2][2][32]
{
  const int bid = blockIdx.x;        // 0..127
  const int d   = bid >> 6;
  const int sl  = (bid >> 1) & 31;
  const int bh  = bid & 1;
  const int tid = threadIdx.x;
  const int gl  = tid >> 4;          // 0..31 (gate-row within slice)
  const int bl  = tid & 15;          // batch within half
  const int gt  = gl >> 3;           // 0=i,1=f,2=g,3=o
  const int u   = gl & 7;            // unit within slice
  const int grow = gt * 256 + sl * 8 + u;     // row in Whh
  const float* __restrict__ whh = d ? whh_b : whh_f;

  __shared__ float w_lds[32][260];   // padded: conflict-free
  __shared__ float h_lds[16][260];
  __shared__ float part[512];

  // load weight slice: thread (r = tid>>4, c16 = tid&15) loads 4 float4s
  {
    const int r = tid >> 4, c16 = tid & 15;
    const int rrow = (r >> 3) * 256 + sl * 8 + (r & 7);
    const float4* src = (const float4*)(whh + (size_t)rrow * H_);
#pragma unroll
    for (int i = 0; i < 4; ++i) {
      float4 v = src[c16 * 4 + i];
      w_lds[r][c16 * 16 + 4 * i + 0] = v.x;
      w_lds[r][c16 * 16 + 4 * i + 1] = v.y;
      w_lds[r][c16 * 16 + 4 * i + 2] = v.z;
      w_lds[r][c16 * 16 + 4 * i + 3] = v.w;
    }
  }
  for (int idx = tid; idx < 16 * 260; idx += 512)
    ((float*)h_lds)[idx] = 0.f;
  __syncthreads();

  float c = 0.f;
  const int fbase = (d * 2 + bh) * 32;
  float* hgrp = h_all + (size_t)(d * 2 + bh) * (L_ * 16 * 256);  // [512][16][256]

  for (int s = 0; s < L_; ++s) {
    const int t = d ? (L_ - 1 - s) : s;

    float acc = xg[((size_t)((bh * 16 + bl) * L_ + t)) * XGLD + d * 1024 + grow];

#pragma unroll 8
    for (int k4 = 0; k4 < 64; ++k4) {
      float4 w4 = *(const float4*)&w_lds[gl][k4 * 4];
      float4 h4 = *(const float4*)&h_lds[bl][k4 * 4];
      acc += w4.x * h4.x + w4.y * h4.y + w4.z * h4.z + w4.w * h4.w;
    }
    part[tid] = acc;
    __syncthreads();

    if (tid < 128) {                 // tid = u*16 + bl
      float gi = sigmoidf_(part[tid]);
      float gf = sigmoidf_(part[128 + tid]);
      float gg = tanhf(part[256 + tid]);
      float go = sigmoidf_(part[384 + tid]);
      c = gf * c + gi * gg;
      float h = go * tanhf(c);
      int uu = tid >> 4, bb = tid & 15;
      __hip_atomic_store(&hgrp[((size_t)t * 16 + bb) * 256 + sl * 8 + uu], h,
                         __ATOMIC_RELAXED, __HIP_MEMORY_SCOPE_AGENT);
    }
    asm volatile("s_waitcnt vmcnt(0)" ::: "memory");
    __syncthreads();
    if (tid == 0)
      __hip_atomic_store(&flags[fbase + sl], s + 1,
                         __ATOMIC_RELAXED, __HIP_MEMORY_SCOPE_AGENT);

    if (s == L_ - 1) break;

    if (tid < 32 && tid != sl) {
      while (__hip_atomic_load(&flags[fbase + tid],
                               __ATOMIC_RELAXED, __HIP_MEMORY_SCOPE_AGENT) < s + 1) {}
    }
    __syncthreads();

    const float* hsrc = hgrp + (size_t)t * 16 * 256;   // [16][256]
    for (int idx = tid; idx < 16 * 256; idx += 512) {
      float v = __hip_atomic_load(&hsrc[idx],
                                  __ATOMIC_RELAXED, __HIP_MEMORY_SCOPE_AGENT);
      h_lds[idx >> 8][idx & 255] = v;
    }
    __syncthreads();
  }
}

// ---------- emissions: em[b][t][tag] = b_out + h_f.Wout_f + h_b.Wout_b ----------
__global__ __launch_bounds__(256) void emis_kernel(
    const float* __restrict__ h_all,  // [2][2][512][16][256]
    const float* __restrict__ wout,   // [4][512]
    const float* __restrict__ bout,   // [4]
    float* __restrict__ em)           // [32][512][4]
{
  __shared__ float ws[4 * 512];
  int tid = threadIdx.x;
  for (int idx = tid; idx < 2048; idx += 256) ws[idx] = wout[idx];
  __syncthreads();

  int wv = blockIdx.x * 4 + (tid >> 6);     // (b,t) index 0..16383
  int lane = tid & 63;
  int b = wv >> 9, t = wv & 511;
  int bh = b >> 4, bl = b & 15;
  const float* hf = h_all + ((size_t)(0 + bh) * L_ * 16 + (size_t)t * 16 + bl) * 256;
  const float* hb = h_all + ((size_t)(2 + bh) * L_ * 16 + (size_t)t * 16 + bl) * 256;

  float p0 = 0.f, p1 = 0.f, p2 = 0.f, p3 = 0.f;
#pragma unroll
  for (int i = 0; i < 4; ++i) {
    int j = i * 64 + lane;
    float hfv = hf[j], hbv = hb[j];
    p0 += hfv * ws[0 * 512 + j] + hbv * ws[0 * 512 + 256 + j];
    p1 += hfv * ws[1 * 512 + j] + hbv * ws[1 * 512 + 256 + j];
    p2 += hfv * ws[2 * 512 + j] + hbv * ws[2 * 512 + 256 + j];
    p3 += hfv * ws[3 * 512 + j] + hbv * ws[3 * 512 + 256 + j];
  }
#pragma unroll
  for (int m = 1; m < 64; m <<= 1) {
    p0 += __shfl_xor(p0, m, 64);
    p1 += __shfl_xor(p1, m, 64);
    p2 += __shfl_xor(p2, m, 64);
    p3 += __shfl_xor(p3, m, 64);
  }
  if (lane == 0) {
    float* ep = em + (size_t)wv * 4;
    ep[0] = p0 + bout[0]; ep[1] = p1 + bout[1];
    ep[2] = p2 + bout[2]; ep[3] = p3 + bout[3];
  }
}

// ---------- Viterbi decode ----------
__global__ __launch_bounds__(64) void viterbi_kernel(
    const float* __restrict__ em,      // [32][512][4]  (bias included)
    const float* __restrict__ trans,   // [4][4]
    const float* __restrict__ strans,  // [4]
    const float* __restrict__ etrans,  // [4]
    const int*   __restrict__ mask,    // [32][512]
    int* __restrict__ hist,            // [32][512][4]
    int* __restrict__ out)             // [32][512]
{
  int b = threadIdx.x;
  if (b >= B_) return;

  const float* emb2 = em + (size_t)b * L_ * 4;

  float tr[4][4];
#pragma unroll
  for (int i = 0; i < 4; ++i)
#pragma unroll
    for (int jj = 0; jj < 4; ++jj) tr[i][jj] = trans[i * 4 + jj];

  float sc[4];
#pragma unroll
  for (int tag = 0; tag < 4; ++tag)
    sc[tag] = strans[tag] + emb2[tag];

  for (int t = 1; t < L_; ++t) {
    float ns[4];
#pragma unroll
    for (int to = 0; to < 4; ++to) {
      float best = sc[0] + tr[0][to];
      int bf = 0;
#pragma unroll
      for (int fr = 1; fr < 4; ++fr) {
        float v = sc[fr] + tr[fr][to];
        if (v > best) { best = v; bf = fr; }
      }
      ns[to] = best + emb2[t * 4 + to];
      hist[((size_t)b * L_ + t) * 4 + to] = bf;
    }
    int mt = mask[b * L_ + t];
#pragma unroll
    for (int to = 0; to < 4; ++to) sc[to] = mt ? ns[to] : sc[to];
  }

#pragma unroll
  for (int tag = 0; tag < 4; ++tag) sc[tag] += etrans[tag];
  int cur = 0;
  float best = sc[0];
#pragma unroll
  for (int i = 1; i < 4; ++i)
    if (sc[i] > best) { best = sc[i]; cur = i; }

  out[b * L_ + (L_ - 1)] = cur * (mask[b * L_ + (L_ - 1)] ? 1 : 0);
  for (int t = L_ - 1; t >= 1; --t) {
    if (mask[b * L_ + t]) cur = hist[((size_t)b * L_ + t) * 4 + cur];
    out[b * L_ + (t - 1)] = cur * (mask[b * L_ + (t - 1)] ? 1 : 0);
  }
}

extern "C" void kernel_launch(void* const* d_in, const int* in_sizes, int n_in,
                              void* d_out, int out_size, void* d_ws, size_t ws_size,
                              hipStream_t stream) {
  const int*   word_ids = (const int*)d_in[0];
  const int*   mask     = (const int*)d_in[1];
  // d_in[2] label_ids: unused
  const float* emb   = (const float*)d_in[3];
  const float* Wih_f = (const float*)d_in[4];
  const float* Whh_f = (const float*)d_in[5];
  const float* b_f   = (const float*)d_in[6];
  const float* Wih_b = (const float*)d_in[7];
  const float* Whh_b = (const float*)d_in[8];
  const float* b_b   = (const float*)d_in[9];
  const float* W_out = (const float*)d_in[10];
  const float* b_out = (const float*)d_in[11];
  const float* trans = (const float*)d_in[12];
  const float* strans = (const float*)d_in[13];
  const float* etrans = (const float*)d_in[14];
  int* out = (int*)d_out;

  float* xg    = (float*)d_ws;                             // 128 MiB
  float* h_all = xg + (size_t)NTOK * XGLD;                 // 2*2*512*16*256 = 33.5 MiB
  float* em    = h_all + (size_t)4 * L_ * 16 * 256;        // 256 KiB
  int*   hist  = (int*)(em + (size_t)B_ * L_ * T_);        // 256 KiB
  int*   flags = hist + (size_t)B_ * L_ * T_;              // 512 B

  init_flags<<<1, 128, 0, stream>>>(flags);
  xproj_kernel<<<dim3(32, 256), 256, 0, stream>>>(word_ids, emb, Wih_f, Wih_b, b_f, b_b, xg);
  lstm_kernel<<<128, 512, 0, stream>>>(xg, Whh_f, Whh_b, h_all, flags);
  emis_kernel<<<4096, 256, 0, stream>>>(h_all, W_out, b_out, em);
  viterbi_kernel<<<1, 64, 0, stream>>>(em, trans, strans, etrans, mask, hist, out);
}

// Round 5
// 3302.630 us; speedup vs baseline: 6.7373x; 1.1518x over previous
//
#include <hip/hip_runtime.h>
#include <math.h>

#define B_   32
#define L_   512
#define E_   300
#define H_   256
#define T_   4
#define NTOK 16384  // B*L
#define XGLD 2048   // 2 directions * 4H

__device__ __forceinline__ float sigmoidf_(float x) { return 1.0f / (1.0f + expf(-x)); }

// ---------- stage A: xg[row][d*1024+g] = emb[wid[row]] . Wih_d[g] + b_d[g] ----------
#define BM 64
#define BN 64
#define BK 20
__global__ __launch_bounds__(256) void xproj_kernel(
    const int*   __restrict__ wid,    // [NTOK]
    const float* __restrict__ emb,    // [V][300]
    const float* __restrict__ wih_f,  // [1024][300]
    const float* __restrict__ wih_b,
    const float* __restrict__ b_f,
    const float* __restrict__ b_b,
    float* __restrict__ xg)           // [NTOK][2048]
{
  __shared__ float As[BM][BK + 1];
  __shared__ float Bs[BK][BN];
  __shared__ int   wid_s[BM];

  int tid = threadIdx.x;
  int m0 = blockIdx.y * BM;
  int n0 = blockIdx.x * BN;            // global col 0..2047
  int d  = n0 >> 10;
  const float* wih  = d ? wih_b : wih_f;
  const float* bias = d ? b_b  : b_f;
  int g0 = n0 & 1023;

  if (tid < BM) wid_s[tid] = wid[m0 + tid];
  __syncthreads();

  int lm = tid >> 2;          // 0..63
  int lk = (tid & 3) * 5;     // 0,5,10,15
  int tx = tid & 15, ty = tid >> 4;

  float acc[4][4] = {};

  for (int k0 = 0; k0 < 300; k0 += BK) {
    const float* erow = emb + (size_t)wid_s[lm] * E_ + k0 + lk;
#pragma unroll
    for (int i = 0; i < 5; ++i) As[lm][lk + i] = erow[i];
    const float* wrow = wih + (size_t)(g0 + lm) * E_ + k0 + lk;
#pragma unroll
    for (int i = 0; i < 5; ++i) Bs[lk + i][lm] = wrow[i];
    __syncthreads();
#pragma unroll
    for (int k = 0; k < BK; ++k) {
      float a0 = As[ty * 4 + 0][k], a1 = As[ty * 4 + 1][k];
      float a2 = As[ty * 4 + 2][k], a3 = As[ty * 4 + 3][k];
      float b0 = Bs[k][tx * 4 + 0], b1 = Bs[k][tx * 4 + 1];
      float b2 = Bs[k][tx * 4 + 2], b3 = Bs[k][tx * 4 + 3];
      acc[0][0] += a0 * b0; acc[0][1] += a0 * b1; acc[0][2] += a0 * b2; acc[0][3] += a0 * b3;
      acc[1][0] += a1 * b0; acc[1][1] += a1 * b1; acc[1][2] += a1 * b2; acc[1][3] += a1 * b3;
      acc[2][0] += a2 * b0; acc[2][1] += a2 * b1; acc[2][2] += a2 * b2; acc[2][3] += a2 * b3;
      acc[3][0] += a3 * b0; acc[3][1] += a3 * b1; acc[3][2] += a3 * b2; acc[3][3] += a3 * b3;
    }
    __syncthreads();
  }

#pragma unroll
  for (int i = 0; i < 4; ++i) {
    int row = m0 + ty * 4 + i;
    float* op = xg + (size_t)row * XGLD + n0 + tx * 4;
#pragma unroll
    for (int jj = 0; jj < 4; ++jj)
      op[jj] = acc[i][jj] + bias[g0 + tx * 4 + jj];
  }
}

// ---------- flag init (replay-safe zeroing each launch) ----------
__global__ __launch_bounds__(128) void init_flags(int* flags) { flags[threadIdx.x] = 0; }

// ---------- stage B: LSTM, register-tiled (4 rows x 4 batches), LDS weights,
//            LLC relaxed-atomic h exchange (round-4 proven sync skeleton) ----------
// Block = (d, slice sl of 8 units = 32 gate rows, batch-half bh of 16).
// 256 threads: tid = kp*32 + cg*8 + rg; kp in [0,8) k-chunk, cg in [0,4) batch
// quad, rg in [0,8) row quad. Thread computes 4x4 outer-product tile over its
// 32-deep k-chunk: 2 ds_read_b128 per 16 FMAs.
__global__ __launch_bounds__(256) void lstm_kernel(
    const float* __restrict__ xg,     // [NTOK][2048]
    const float* __restrict__ whh_f,  // [1024][256]
    const float* __restrict__ whh_b,  // [1024][256]
    float*       h_all,               // [2][2][512][16][256]  (d, bh, t, bl, j)
    int*         flags)               // [2][2][32]
{
  const int bid = blockIdx.x;        // 0..127
  const int d   = bid >> 6;
  const int sl  = (bid >> 1) & 31;
  const int bh  = bid & 1;
  const int tid = threadIdx.x;
  const int kp  = tid >> 5;          // 0..7
  const int cg  = (tid >> 3) & 3;    // 0..3
  const int rg  = tid & 7;           // 0..7
  const float* __restrict__ whh = d ? whh_b : whh_f;

  __shared__ float w_lds[256 * 32];      // w_t[k][row]   row = gt*8+u
  __shared__ float h_lds[256 * 16];      // h_t[k][bl]
  __shared__ float part_lds[8 * 16 * 33];// part[kp][bl][row] (padded 33)

  // ---- load + transpose weight slice into LDS (once) ----
  {
    const int row_l = tid & 31;          // gt*8+u
    const int kq    = tid >> 5;          // 0..7
    const int grow_l = (row_l >> 3) * 256 + sl * 8 + (row_l & 7);
    const float* src = whh + (size_t)grow_l * H_;
#pragma unroll
    for (int i = 0; i < 8; ++i) {
      const int kb = kq * 32 + i * 4;
      float4 v = *(const float4*)(src + kb);
      w_lds[(kb + 0) * 32 + row_l] = v.x;
      w_lds[(kb + 1) * 32 + row_l] = v.y;
      w_lds[(kb + 2) * 32 + row_l] = v.z;
      w_lds[(kb + 3) * 32 + row_l] = v.w;
    }
  }
  for (int idx = tid; idx < 256 * 16; idx += 256) h_lds[idx] = 0.f;
  __syncthreads();

  float c = 0.f;
  const int fbase = (d * 2 + bh) * 32;
  float* hgrp = h_all + (size_t)(d * 2 + bh) * (L_ * 16 * 256);  // [512][16][256]

  const int u_r  = tid >> 4;   // reduce-phase unit (tid<128)
  const int bl_r = tid & 15;   // reduce-phase batch

  const int kbase = kp * 32;

  for (int s = 0; s < L_; ++s) {
    const int t = d ? (L_ - 1 - s) : s;

    // early xg loads for reduce phase (consumed after the barrier)
    float xg0 = 0.f, xg1 = 0.f, xg2 = 0.f, xg3 = 0.f;
    if (tid < 128) {
      const float* xp = xg + ((size_t)((bh * 16 + bl_r) * L_ + t)) * XGLD
                        + d * 1024 + sl * 8 + u_r;
      xg0 = xp[0]; xg1 = xp[256]; xg2 = xp[512]; xg3 = xp[768];
    }

    // ---- 4x4 register-tiled partial GEMM over k-chunk ----
    float acc[4][4] = {};
#pragma unroll 8
    for (int i = 0; i < 32; ++i) {
      const int k = kbase + i;
      float4 wv = *(const float4*)&w_lds[k * 32 + rg * 4];
      float4 hv = *(const float4*)&h_lds[k * 16 + cg * 4];
      acc[0][0] += wv.x * hv.x; acc[0][1] += wv.x * hv.y;
      acc[0][2] += wv.x * hv.z; acc[0][3] += wv.x * hv.w;
      acc[1][0] += wv.y * hv.x; acc[1][1] += wv.y * hv.y;
      acc[1][2] += wv.y * hv.z; acc[1][3] += wv.y * hv.w;
      acc[2][0] += wv.z * hv.x; acc[2][1] += wv.z * hv.y;
      acc[2][2] += wv.z * hv.z; acc[2][3] += wv.z * hv.w;
      acc[3][0] += wv.w * hv.x; acc[3][1] += wv.w * hv.y;
      acc[3][2] += wv.w * hv.z; acc[3][3] += wv.w * hv.w;
    }
    // write partials: part[kp][bl][row], bl = cg*4+cc, row = rg*4+rr
#pragma unroll
    for (int rr = 0; rr < 4; ++rr)
#pragma unroll
      for (int cc = 0; cc < 4; ++cc)
        part_lds[kp * 528 + (cg * 4 + cc) * 33 + rg * 4 + rr] = acc[rr][cc];
    __syncthreads();

    // ---- reduce over kp, activate, update state, publish h ----
    if (tid < 128) {
      float g0 = 0.f, g1 = 0.f, g2 = 0.f, g3 = 0.f;
#pragma unroll
      for (int kp2 = 0; kp2 < 8; ++kp2) {
        const float* pp = &part_lds[kp2 * 528 + bl_r * 33 + u_r];
        g0 += pp[0]; g1 += pp[8]; g2 += pp[16]; g3 += pp[24];
      }
      g0 += xg0; g1 += xg1; g2 += xg2; g3 += xg3;
      float gi = sigmoidf_(g0);
      float gf = sigmoidf_(g1);
      float gg = tanhf(g2);
      float go = sigmoidf_(g3);
      c = gf * c + gi * gg;
      float h = go * tanhf(c);
      __hip_atomic_store(&hgrp[((size_t)t * 16 + bl_r) * 256 + sl * 8 + u_r], h,
                         __ATOMIC_RELAXED, __HIP_MEMORY_SCOPE_AGENT);
    }
    asm volatile("s_waitcnt vmcnt(0)" ::: "memory");
    __syncthreads();
    if (tid == 0)
      __hip_atomic_store(&flags[fbase + sl], s + 1,
                         __ATOMIC_RELAXED, __HIP_MEMORY_SCOPE_AGENT);

    if (s == L_ - 1) break;

    if (tid < 32 && tid != sl) {
      while (__hip_atomic_load(&flags[fbase + tid],
                               __ATOMIC_RELAXED, __HIP_MEMORY_SCOPE_AGENT) < s + 1) {}
    }
    __syncthreads();

    // reload full h[t] into h_t[k=j][bl]
    {
      const float* hsrc = hgrp + (size_t)t * 16 * 256;   // [16][256]
      const int bbl = tid & 15;
      const int j0  = (tid >> 4) * 16;
#pragma unroll
      for (int i = 0; i < 16; ++i) {
        float v = __hip_atomic_load(&hsrc[bbl * 256 + j0 + i],
                                    __ATOMIC_RELAXED, __HIP_MEMORY_SCOPE_AGENT);
        h_lds[(j0 + i) * 16 + bbl] = v;
      }
    }
    __syncthreads();
  }
}

// ---------- emissions: em[b][t][tag] = b_out + h_f.Wout_f + h_b.Wout_b ----------
__global__ __launch_bounds__(256) void emis_kernel(
    const float* __restrict__ h_all,  // [2][2][512][16][256]
    const float* __restrict__ wout,   // [4][512]
    const float* __restrict__ bout,   // [4]
    float* __restrict__ em)           // [32][512][4]
{
  __shared__ float ws[4 * 512];
  int tid = threadIdx.x;
  for (int idx = tid; idx < 2048; idx += 256) ws[idx] = wout[idx];
  __syncthreads();

  int wv = blockIdx.x * 4 + (tid >> 6);     // (b,t) index 0..16383
  int lane = tid & 63;
  int b = wv >> 9, t = wv & 511;
  int bh = b >> 4, bl = b & 15;
  const float* hf = h_all + ((size_t)(0 + bh) * L_ * 16 + (size_t)t * 16 + bl) * 256;
  const float* hb = h_all + ((size_t)(2 + bh) * L_ * 16 + (size_t)t * 16 + bl) * 256;

  float p0 = 0.f, p1 = 0.f, p2 = 0.f, p3 = 0.f;
#pragma unroll
  for (int i = 0; i < 4; ++i) {
    int j = i * 64 + lane;
    float hfv = hf[j], hbv = hb[j];
    p0 += hfv * ws[0 * 512 + j] + hbv * ws[0 * 512 + 256 + j];
    p1 += hfv * ws[1 * 512 + j] + hbv * ws[1 * 512 + 256 + j];
    p2 += hfv * ws[2 * 512 + j] + hbv * ws[2 * 512 + 256 + j];
    p3 += hfv * ws[3 * 512 + j] + hbv * ws[3 * 512 + 256 + j];
  }
#pragma unroll
  for (int m = 1; m < 64; m <<= 1) {
    p0 += __shfl_xor(p0, m, 64);
    p1 += __shfl_xor(p1, m, 64);
    p2 += __shfl_xor(p2, m, 64);
    p3 += __shfl_xor(p3, m, 64);
  }
  if (lane == 0) {
    float* ep = em + (size_t)wv * 4;
    ep[0] = p0 + bout[0]; ep[1] = p1 + bout[1];
    ep[2] = p2 + bout[2]; ep[3] = p3 + bout[3];
  }
}

// ---------- Viterbi decode ----------
__global__ __launch_bounds__(64) void viterbi_kernel(
    const float* __restrict__ em,      // [32][512][4]  (bias included)
    const float* __restrict__ trans,   // [4][4]
    const float* __restrict__ strans,  // [4]
    const float* __restrict__ etrans,  // [4]
    const int*   __restrict__ mask,    // [32][512]
    int* __restrict__ hist,            // [32][512][4]
    int* __restrict__ out)             // [32][512]
{
  int b = threadIdx.x;
  if (b >= B_) return;

  const float* emb2 = em + (size_t)b * L_ * 4;

  float tr[4][4];
#pragma unroll
  for (int i = 0; i < 4; ++i)
#pragma unroll
    for (int jj = 0; jj < 4; ++jj) tr[i][jj] = trans[i * 4 + jj];

  float sc[4];
#pragma unroll
  for (int tag = 0; tag < 4; ++tag)
    sc[tag] = strans[tag] + emb2[tag];

  for (int t = 1; t < L_; ++t) {
    float ns[4];
#pragma unroll
    for (int to = 0; to < 4; ++to) {
      float best = sc[0] + tr[0][to];
      int bf = 0;
#pragma unroll
      for (int fr = 1; fr < 4; ++fr) {
        float v = sc[fr] + tr[fr][to];
        if (v > best) { best = v; bf = fr; }
      }
      ns[to] = best + emb2[t * 4 + to];
      hist[((size_t)b * L_ + t) * 4 + to] = bf;
    }
    int mt = mask[b * L_ + t];
#pragma unroll
    for (int to = 0; to < 4; ++to) sc[to] = mt ? ns[to] : sc[to];
  }

#pragma unroll
  for (int tag = 0; tag < 4; ++tag) sc[tag] += etrans[tag];
  int cur = 0;
  float best = sc[0];
#pragma unroll
  for (int i = 1; i < 4; ++i)
    if (sc[i] > best) { best = sc[i]; cur = i; }

  out[b * L_ + (L_ - 1)] = cur * (mask[b * L_ + (L_ - 1)] ? 1 : 0);
  for (int t = L_ - 1; t >= 1; --t) {
    if (mask[b * L_ + t]) cur = hist[((size_t)b * L_ + t) * 4 + cur];
    out[b * L_ + (t - 1)] = cur * (mask[b * L_ + (t - 1)] ? 1 : 0);
  }
}

extern "C" void kernel_launch(void* const* d_in, const int* in_sizes, int n_in,
                              void* d_out, int out_size, void* d_ws, size_t ws_size,
                              hipStream_t stream) {
  const int*   word_ids = (const int*)d_in[0];
  const int*   mask     = (const int*)d_in[1];
  // d_in[2] label_ids: unused
  const float* emb   = (const float*)d_in[3];
  const float* Wih_f = (const float*)d_in[4];
  const float* Whh_f = (const float*)d_in[5];
  const float* b_f   = (const float*)d_in[6];
  const float* Wih_b = (const float*)d_in[7];
  const float* Whh_b = (const float*)d_in[8];
  const float* b_b   = (const float*)d_in[9];
  const float* W_out = (const float*)d_in[10];
  const float* b_out = (const float*)d_in[11];
  const float* trans = (const float*)d_in[12];
  const float* strans = (const float*)d_in[13];
  const float* etrans = (const float*)d_in[14];
  int* out = (int*)d_out;

  float* xg    = (float*)d_ws;                             // 128 MiB
  float* h_all = xg + (size_t)NTOK * XGLD;                 // 33.5 MiB
  float* em    = h_all + (size_t)4 * L_ * 16 * 256;        // 256 KiB
  int*   hist  = (int*)(em + (size_t)B_ * L_ * T_);        // 256 KiB
  int*   flags = hist + (size_t)B_ * L_ * T_;              // 512 B

  init_flags<<<1, 128, 0, stream>>>(flags);
  xproj_kernel<<<dim3(32, 256), 256, 0, stream>>>(word_ids, emb, Wih_f, Wih_b, b_f, b_b, xg);
  lstm_kernel<<<128, 256, 0, stream>>>(xg, Whh_f, Whh_b, h_all, flags);
  emis_kernel<<<4096, 256, 0, stream>>>(h_all, W_out, b_out, em);
  viterbi_kernel<<<1, 64, 0, stream>>>(em, trans, strans, etrans, mask, hist, out);
}

// Round 6
// 2619.196 us; speedup vs baseline: 8.4953x; 1.2609x over previous
//
#include <hip/hip_runtime.h>
#include <math.h>

#define B_   32
#define L_   512
#define E_   300
#define H_   256
#define T_   4
#define NTOK 16384  // B*L
#define XGLD 2048   // 2 directions * 4H

typedef float f32x4 __attribute__((ext_vector_type(4)));

__device__ __forceinline__ float sigmoidf_(float x) { return 1.0f / (1.0f + expf(-x)); }

// LLC-coherent (agent-scope) vector ops: sc0 sc1 bypass L1/L2 like relaxed
// agent atomics, but vectorized. Caller must s_waitcnt vmcnt before using loads.
__device__ __forceinline__ void llc_store_f32(float* p, float v) {
  asm volatile("global_store_dword %0, %1, off sc0 sc1" :: "v"(p), "v"(v) : "memory");
}
__device__ __forceinline__ f32x4 llc_load_f32x4(const float* p) {
  f32x4 r;
  asm volatile("global_load_dwordx4 %0, %1, off sc0 sc1" : "=&v"(r) : "v"(p) : "memory");
  return r;
}

// ---------- stage A: xg[row][d*1024+g] = emb[wid[row]] . Wih_d[g] + b_d[g] ----------
#define BM 64
#define BN 64
#define BK 20
__global__ __launch_bounds__(256) void xproj_kernel(
    const int*   __restrict__ wid,    // [NTOK]
    const float* __restrict__ emb,    // [V][300]
    const float* __restrict__ wih_f,  // [1024][300]
    const float* __restrict__ wih_b,
    const float* __restrict__ b_f,
    const float* __restrict__ b_b,
    float* __restrict__ xg)           // [NTOK][2048]
{
  __shared__ float As[BM][BK + 1];
  __shared__ float Bs[BK][BN];
  __shared__ int   wid_s[BM];

  int tid = threadIdx.x;
  int m0 = blockIdx.y * BM;
  int n0 = blockIdx.x * BN;            // global col 0..2047
  int d  = n0 >> 10;
  const float* wih  = d ? wih_b : wih_f;
  const float* bias = d ? b_b  : b_f;
  int g0 = n0 & 1023;

  if (tid < BM) wid_s[tid] = wid[m0 + tid];
  __syncthreads();

  int lm = tid >> 2;          // 0..63
  int lk = (tid & 3) * 5;     // 0,5,10,15
  int tx = tid & 15, ty = tid >> 4;

  float acc[4][4] = {};

  for (int k0 = 0; k0 < 300; k0 += BK) {
    const float* erow = emb + (size_t)wid_s[lm] * E_ + k0 + lk;
#pragma unroll
    for (int i = 0; i < 5; ++i) As[lm][lk + i] = erow[i];
    const float* wrow = wih + (size_t)(g0 + lm) * E_ + k0 + lk;
#pragma unroll
    for (int i = 0; i < 5; ++i) Bs[lk + i][lm] = wrow[i];
    __syncthreads();
#pragma unroll
    for (int k = 0; k < BK; ++k) {
      float a0 = As[ty * 4 + 0][k], a1 = As[ty * 4 + 1][k];
      float a2 = As[ty * 4 + 2][k], a3 = As[ty * 4 + 3][k];
      float b0 = Bs[k][tx * 4 + 0], b1 = Bs[k][tx * 4 + 1];
      float b2 = Bs[k][tx * 4 + 2], b3 = Bs[k][tx * 4 + 3];
      acc[0][0] += a0 * b0; acc[0][1] += a0 * b1; acc[0][2] += a0 * b2; acc[0][3] += a0 * b3;
      acc[1][0] += a1 * b0; acc[1][1] += a1 * b1; acc[1][2] += a1 * b2; acc[1][3] += a1 * b3;
      acc[2][0] += a2 * b0; acc[2][1] += a2 * b1; acc[2][2] += a2 * b2; acc[2][3] += a2 * b3;
      acc[3][0] += a3 * b0; acc[3][1] += a3 * b1; acc[3][2] += a3 * b2; acc[3][3] += a3 * b3;
    }
    __syncthreads();
  }

#pragma unroll
  for (int i = 0; i < 4; ++i) {
    int row = m0 + ty * 4 + i;
    float* op = xg + (size_t)row * XGLD + n0 + tx * 4;
#pragma unroll
    for (int jj = 0; jj < 4; ++jj)
      op[jj] = acc[i][jj] + bias[g0 + tx * 4 + jj];
  }
}

// ---------- flag init (replay-safe zeroing each launch) ----------
__global__ __launch_bounds__(128) void init_flags(int* flags) { flags[threadIdx.x] = 0; }

// ---------- stage B: LSTM. 16-block sync groups, LDS weights, vectorized LLC exchange --
// Block = (d, slice sl of 16 units = 64 gate rows, batch-half bh of 16 batches).
// 512 threads: tid = kp*64 + cg*16 + rg. Wave = one kp (k-chunk of 32).
// Tile: 4 rows x 4 batches. Partials in [kp][bl][68] (b128 writes, even banks).
// h exchanged via h_all[t][j][bl] with sc0/sc1 dwordx4 (LLC-coherent, vectorized).
__global__ __launch_bounds__(512, 1) void lstm_kernel(
    const float* __restrict__ xg,     // [NTOK][2048]
    const float* __restrict__ whh_f,  // [1024][256]
    const float* __restrict__ whh_b,  // [1024][256]
    float*       h_all,               // [4 grp][512 t][256 j][16 bl]
    int*         flags)               // [4 grp][16]
{
  const int bid = blockIdx.x;        // 0..63
  const int d   = bid >> 5;
  const int sl  = (bid >> 1) & 15;
  const int bh  = bid & 1;
  const int tid = threadIdx.x;
  const int kp  = tid >> 6;          // 0..7 (wave id)
  const int cg  = (tid >> 4) & 3;    // batch quad
  const int rg  = tid & 15;          // row quad
  const float* __restrict__ whh = d ? whh_b : whh_f;

  __shared__ float w_lds[256 * 64];        // w_t[k][row], row = gt*16+u   (64 KB)
  __shared__ float h_lds[256 * 20];        // h_t[k][bl(16)+pad]           (20 KB)
  __shared__ float part_lds[8 * 16 * 68];  // part[kp][bl][row(64)+pad]    (34.8 KB)

  // ---- load + transpose weight slice into LDS (once) ----
  {
    const int row_l = tid & 63;            // gt*16 + u
    const int kq    = tid >> 6;            // 0..7, 32 k each
    const int grow  = (row_l >> 4) * 256 + sl * 16 + (row_l & 15);
    const float* src = whh + (size_t)grow * H_ + kq * 32;
#pragma unroll
    for (int i = 0; i < 8; ++i) {
      f32x4 v = *(const f32x4*)(src + i * 4);
      const int kb = kq * 32 + i * 4;
      w_lds[(kb + 0) * 64 + row_l] = v.x;
      w_lds[(kb + 1) * 64 + row_l] = v.y;
      w_lds[(kb + 2) * 64 + row_l] = v.z;
      w_lds[(kb + 3) * 64 + row_l] = v.w;
    }
  }
  for (int idx = tid; idx < 256 * 20; idx += 512) h_lds[idx] = 0.f;
  __syncthreads();

  float c = 0.f;
  const int fbase = (d * 2 + bh) * 16;
  float* hgrp = h_all + (size_t)(d * 2 + bh) * (L_ * 256 * 16);  // [512][256][16]

  const int u_r  = tid >> 4;   // reduce-phase unit (tid<256)
  const int bl_r = tid & 15;   // reduce-phase batch
  const int kbase = kp * 32;

  for (int s = 0; s < L_; ++s) {
    const int t = d ? (L_ - 1 - s) : s;

    // early xg loads (normal cached loads; latency hidden under GEMM)
    float xg0 = 0.f, xg1 = 0.f, xg2 = 0.f, xg3 = 0.f;
    if (tid < 256) {
      const float* xp = xg + ((size_t)((bh * 16 + bl_r) * L_ + t)) * XGLD
                        + d * 1024 + sl * 16 + u_r;
      xg0 = xp[0]; xg1 = xp[256]; xg2 = xp[512]; xg3 = xp[768];
    }

    // ---- 4x4 register-tiled partial GEMM over this wave's 32-deep k-chunk ----
    float acc[4][4] = {};
#pragma unroll 8
    for (int i = 0; i < 32; ++i) {
      const int k = kbase + i;
      f32x4 wv = *(const f32x4*)&w_lds[k * 64 + rg * 4];
      f32x4 hv = *(const f32x4*)&h_lds[k * 20 + cg * 4];
      acc[0][0] += wv.x * hv.x; acc[0][1] += wv.x * hv.y;
      acc[0][2] += wv.x * hv.z; acc[0][3] += wv.x * hv.w;
      acc[1][0] += wv.y * hv.x; acc[1][1] += wv.y * hv.y;
      acc[1][2] += wv.y * hv.z; acc[1][3] += wv.y * hv.w;
      acc[2][0] += wv.z * hv.x; acc[2][1] += wv.z * hv.y;
      acc[2][2] += wv.z * hv.z; acc[2][3] += wv.z * hv.w;
      acc[3][0] += wv.w * hv.x; acc[3][1] += wv.w * hv.y;
      acc[3][2] += wv.w * hv.z; acc[3][3] += wv.w * hv.w;
    }
    // partials as b128: part[kp][bl = cg*4+cc][row rg*4 .. +3]
#pragma unroll
    for (int cc = 0; cc < 4; ++cc) {
      f32x4 pv = {acc[0][cc], acc[1][cc], acc[2][cc], acc[3][cc]};
      *(f32x4*)&part_lds[kp * 1088 + (cg * 4 + cc) * 68 + rg * 4] = pv;
    }
    __syncthreads();

    // ---- reduce over kp, activate, update state, publish h to LLC ----
    if (tid < 256) {
      float g0 = xg0, g1 = xg1, g2 = xg2, g3 = xg3;
#pragma unroll
      for (int k2 = 0; k2 < 8; ++k2) {
        const float* pp = &part_lds[k2 * 1088 + bl_r * 68 + u_r];
        g0 += pp[0]; g1 += pp[16]; g2 += pp[32]; g3 += pp[48];
      }
      float gi = sigmoidf_(g0);
      float gf = sigmoidf_(g1);
      float gg = tanhf(g2);
      float go = sigmoidf_(g3);
      c = gf * c + gi * gg;
      float h = go * tanhf(c);
      llc_store_f32(&hgrp[((size_t)t * 256 + sl * 16 + u_r) * 16 + bl_r], h);
    }
    asm volatile("s_waitcnt vmcnt(0)" ::: "memory");
    __syncthreads();
    if (tid == 0)
      __hip_atomic_store(&flags[fbase + sl], s + 1,
                         __ATOMIC_RELAXED, __HIP_MEMORY_SCOPE_AGENT);

    if (s == L_ - 1) break;

    // wait for the 15 partner slices of this step
    if (tid < 16 && tid != sl) {
      while (__hip_atomic_load(&flags[fbase + tid],
                               __ATOMIC_RELAXED, __HIP_MEMORY_SCOPE_AGENT) < s + 1) {}
    }
    __syncthreads();

    // reload full h[t] (16 KB) via LLC dwordx4, store transposed-free to h_lds
    {
      const float* hsrc = hgrp + (size_t)t * 4096;   // [256 j][16 bl]
      const int j0 = tid >> 2, bq = tid & 3;
      f32x4 v0 = llc_load_f32x4(hsrc + j0 * 16 + bq * 4);
      f32x4 v1 = llc_load_f32x4(hsrc + (j0 + 128) * 16 + bq * 4);
      asm volatile("s_waitcnt vmcnt(0)" ::: "memory");
      __builtin_amdgcn_sched_barrier(0);
      *(f32x4*)&h_lds[j0 * 20 + bq * 4] = v0;
      *(f32x4*)&h_lds[(j0 + 128) * 20 + bq * 4] = v1;
    }
    __syncthreads();
  }
}

// ---------- emissions: per (t, bh) tile, em[b][t][tag] = bout + h_f.Wf + h_b.Wb ------
__global__ __launch_bounds__(256) void emis_kernel(
    const float* __restrict__ h_all,  // [4][512][256][16]
    const float* __restrict__ wout,   // [4][512]
    const float* __restrict__ bout,   // [4]
    float* __restrict__ em)           // [32][512][4]
{
  __shared__ float hf_l[4096];   // [j][bl]
  __shared__ float hb_l[4096];
  __shared__ float wsl[2048];
  __shared__ float red[256];

  const int t  = blockIdx.x >> 1;
  const int bh = blockIdx.x & 1;
  const int tid = threadIdx.x;
  const float* hfp = h_all + ((size_t)(0 + bh) * L_ + t) * 4096;
  const float* hbp = h_all + ((size_t)(2 + bh) * L_ + t) * 4096;

  for (int i = tid; i < 1024; i += 256) {
    *(f32x4*)&hf_l[i * 4] = *(const f32x4*)&hfp[i * 4];
    *(f32x4*)&hb_l[i * 4] = *(const f32x4*)&hbp[i * 4];
  }
  for (int i = tid; i < 2048; i += 256) wsl[i] = wout[i];
  __syncthreads();

  const int bl = tid & 15, tag = (tid >> 4) & 3, ch = tid >> 6;
  float s = 0.f;
#pragma unroll 8
  for (int jj = 0; jj < 64; ++jj) {
    const int j = ch * 64 + jj;
    s += hf_l[j * 16 + bl] * wsl[tag * 512 + j]
       + hb_l[j * 16 + bl] * wsl[tag * 512 + 256 + j];
  }
  red[tid] = s;
  __syncthreads();
  if (tid < 64) {
    const int tg = tid >> 4, bb = tid & 15;
    float v = red[tid] + red[tid + 64] + red[tid + 128] + red[tid + 192];
    em[((size_t)(bh * 16 + bb) * L_ + t) * 4 + tg] = v + bout[tg];
  }
}

// ---------- Viterbi decode: one block per batch, em/hist staged in LDS ----------
__global__ __launch_bounds__(64) void viterbi_kernel(
    const float* __restrict__ em,      // [32][512][4]  (bias included)
    const float* __restrict__ trans,   // [4][4]
    const float* __restrict__ strans,  // [4]
    const float* __restrict__ etrans,  // [4]
    const int*   __restrict__ mask,    // [32][512]
    int* __restrict__ out)             // [32][512]
{
  __shared__ float em_l[512 * 4];
  __shared__ int   msk_l[512];
  __shared__ int   hist_l[512 * 4];
  __shared__ int   tags_l[512];

  const int b = blockIdx.x;
  const int tid = threadIdx.x;
  const float* ep = em + (size_t)b * L_ * 4;

  for (int i = tid; i < 512; i += 64) {
    *(f32x4*)&em_l[i * 4] = *(const f32x4*)&ep[i * 4];
    msk_l[i] = mask[b * L_ + i];
  }
  __syncthreads();

  if (tid == 0) {
    float tr[4][4];
#pragma unroll
    for (int i = 0; i < 4; ++i)
#pragma unroll
      for (int jj = 0; jj < 4; ++jj) tr[i][jj] = trans[i * 4 + jj];

    float sc[4];
#pragma unroll
    for (int tag = 0; tag < 4; ++tag) sc[tag] = strans[tag] + em_l[tag];

    for (int t = 1; t < L_; ++t) {
      float ns[4];
#pragma unroll
      for (int to = 0; to < 4; ++to) {
        float best = sc[0] + tr[0][to];
        int bf = 0;
#pragma unroll
        for (int fr = 1; fr < 4; ++fr) {
          float v = sc[fr] + tr[fr][to];
          if (v > best) { best = v; bf = fr; }
        }
        ns[to] = best + em_l[t * 4 + to];
        hist_l[t * 4 + to] = bf;
      }
      const int mt = msk_l[t];
#pragma unroll
      for (int to = 0; to < 4; ++to) sc[to] = mt ? ns[to] : sc[to];
    }

#pragma unroll
    for (int tag = 0; tag < 4; ++tag) sc[tag] += etrans[tag];
    int cur = 0;
    float best = sc[0];
#pragma unroll
    for (int i = 1; i < 4; ++i)
      if (sc[i] > best) { best = sc[i]; cur = i; }

    tags_l[L_ - 1] = msk_l[L_ - 1] ? cur : 0;
    for (int t = L_ - 1; t >= 1; --t) {
      if (msk_l[t]) cur = hist_l[t * 4 + cur];
      tags_l[t - 1] = msk_l[t - 1] ? cur : 0;
    }
  }
  __syncthreads();
  for (int i = tid; i < 512; i += 64) out[b * L_ + i] = tags_l[i];
}

extern "C" void kernel_launch(void* const* d_in, const int* in_sizes, int n_in,
                              void* d_out, int out_size, void* d_ws, size_t ws_size,
                              hipStream_t stream) {
  const int*   word_ids = (const int*)d_in[0];
  const int*   mask     = (const int*)d_in[1];
  // d_in[2] label_ids: unused
  const float* emb   = (const float*)d_in[3];
  const float* Wih_f = (const float*)d_in[4];
  const float* Whh_f = (const float*)d_in[5];
  const float* b_f   = (const float*)d_in[6];
  const float* Wih_b = (const float*)d_in[7];
  const float* Whh_b = (const float*)d_in[8];
  const float* b_b   = (const float*)d_in[9];
  const float* W_out = (const float*)d_in[10];
  const float* b_out = (const float*)d_in[11];
  const float* trans = (const float*)d_in[12];
  const float* strans = (const float*)d_in[13];
  const float* etrans = (const float*)d_in[14];
  int* out = (int*)d_out;

  float* xg    = (float*)d_ws;                             // 128 MiB
  float* h_all = xg + (size_t)NTOK * XGLD;                 // 4*512*4096 f32 = 32 MiB
  float* em    = h_all + (size_t)4 * L_ * 4096;            // 256 KiB
  int*   flags = (int*)(em + (size_t)B_ * L_ * T_);        // 512 B

  init_flags<<<1, 128, 0, stream>>>(flags);
  xproj_kernel<<<dim3(32, 256), 256, 0, stream>>>(word_ids, emb, Wih_f, Wih_b, b_f, b_b, xg);
  lstm_kernel<<<64, 512, 0, stream>>>(xg, Whh_f, Whh_b, h_all, flags);
  emis_kernel<<<1024, 256, 0, stream>>>(h_all, W_out, b_out, em);
  viterbi_kernel<<<32, 64, 0, stream>>>(em, trans, strans, etrans, mask, out);
}

// Round 7
// 2374.881 us; speedup vs baseline: 9.3692x; 1.1029x over previous
//
#include <hip/hip_runtime.h>
#include <math.h>

#define B_   32
#define L_   512
#define E_   300
#define H_   256
#define T_   4
#define NTOK 16384  // B*L
#define XGLD 2048   // 2 directions * 4H
#define SENT 2.0f   // impossible h value: |h| = |sigm*tanh| < 1

typedef float f32x4 __attribute__((ext_vector_type(4)));

__device__ __forceinline__ float sigmoidf_(float x) { return 1.0f / (1.0f + expf(-x)); }

// LLC-coherent (agent-scope) vector ops: sc0 sc1 bypass L1/L2 like relaxed
// agent atomics, but vectorized. Caller must s_waitcnt vmcnt before using loads.
__device__ __forceinline__ void llc_store_f32(float* p, float v) {
  asm volatile("global_store_dword %0, %1, off sc0 sc1" :: "v"(p), "v"(v) : "memory");
}
__device__ __forceinline__ void llc_store_f32x4(float* p, f32x4 v) {
  asm volatile("global_store_dwordx4 %0, %1, off sc0 sc1" :: "v"(p), "v"(v) : "memory");
}
__device__ __forceinline__ f32x4 llc_load_f32x4(const float* p) {
  f32x4 r;
  asm volatile("global_load_dwordx4 %0, %1, off sc0 sc1" : "=&v"(r) : "v"(p) : "memory");
  return r;
}

// ---------- stage A: xg[row][d*1024+g] = emb[wid[row]] . Wih_d[g] + b_d[g] ----------
#define BM 64
#define BN 64
#define BK 20
__global__ __launch_bounds__(256) void xproj_kernel(
    const int*   __restrict__ wid,    // [NTOK]
    const float* __restrict__ emb,    // [V][300]
    const float* __restrict__ wih_f,  // [1024][300]
    const float* __restrict__ wih_b,
    const float* __restrict__ b_f,
    const float* __restrict__ b_b,
    float* __restrict__ xg)           // [NTOK][2048]
{
  __shared__ float As[BM][BK + 1];
  __shared__ float Bs[BK][BN];
  __shared__ int   wid_s[BM];

  int tid = threadIdx.x;
  int m0 = blockIdx.y * BM;
  int n0 = blockIdx.x * BN;            // global col 0..2047
  int d  = n0 >> 10;
  const float* wih  = d ? wih_b : wih_f;
  const float* bias = d ? b_b  : b_f;
  int g0 = n0 & 1023;

  if (tid < BM) wid_s[tid] = wid[m0 + tid];
  __syncthreads();

  int lm = tid >> 2;          // 0..63
  int lk = (tid & 3) * 5;     // 0,5,10,15
  int tx = tid & 15, ty = tid >> 4;

  float acc[4][4] = {};

  for (int k0 = 0; k0 < 300; k0 += BK) {
    const float* erow = emb + (size_t)wid_s[lm] * E_ + k0 + lk;
#pragma unroll
    for (int i = 0; i < 5; ++i) As[lm][lk + i] = erow[i];
    const float* wrow = wih + (size_t)(g0 + lm) * E_ + k0 + lk;
#pragma unroll
    for (int i = 0; i < 5; ++i) Bs[lk + i][lm] = wrow[i];
    __syncthreads();
#pragma unroll
    for (int k = 0; k < BK; ++k) {
      float a0 = As[ty * 4 + 0][k], a1 = As[ty * 4 + 1][k];
      float a2 = As[ty * 4 + 2][k], a3 = As[ty * 4 + 3][k];
      float b0 = Bs[k][tx * 4 + 0], b1 = Bs[k][tx * 4 + 1];
      float b2 = Bs[k][tx * 4 + 2], b3 = Bs[k][tx * 4 + 3];
      acc[0][0] += a0 * b0; acc[0][1] += a0 * b1; acc[0][2] += a0 * b2; acc[0][3] += a0 * b3;
      acc[1][0] += a1 * b0; acc[1][1] += a1 * b1; acc[1][2] += a1 * b2; acc[1][3] += a1 * b3;
      acc[2][0] += a2 * b0; acc[2][1] += a2 * b1; acc[2][2] += a2 * b2; acc[2][3] += a2 * b3;
      acc[3][0] += a3 * b0; acc[3][1] += a3 * b1; acc[3][2] += a3 * b2; acc[3][3] += a3 * b3;
    }
    __syncthreads();
  }

#pragma unroll
  for (int i = 0; i < 4; ++i) {
    int row = m0 + ty * 4 + i;
    float* op = xg + (size_t)row * XGLD + n0 + tx * 4;
#pragma unroll
    for (int jj = 0; jj < 4; ++jj)
      op[jj] = acc[i][jj] + bias[g0 + tx * 4 + jj];
  }
}

// ---------- sentinel fill for h_all (replay-safe, runs every launch) ----------
__global__ __launch_bounds__(256) void fill_sentinel(float* p, int n4) {
  int i = blockIdx.x * 256 + threadIdx.x;
  if (i < n4) {
    f32x4 v = {SENT, SENT, SENT, SENT};
    llc_store_f32x4(p + (size_t)i * 4, v);
  }
}

// ---------- stage B: LSTM. 16-block groups, LDS weights, flagless sentinel sync ------
// Block = (d, slice sl of 16 units = 64 gate rows, batch-half bh of 16 batches).
// 512 threads: tid = kp*64 + cg*16 + rg. Wave = one kp (k-chunk of 32).
// h published to h_all[t][j][bl] via sc0/sc1 stores; partners spin directly on the
// data (sentinel 2.0f marks not-yet-written) -- no flags, no fences.
__global__ __launch_bounds__(512, 1) void lstm_kernel(
    const float* __restrict__ xg,     // [NTOK][2048]
    const float* __restrict__ whh_f,  // [1024][256]
    const float* __restrict__ whh_b,  // [1024][256]
    float*       h_all)               // [4 grp][512 t][256 j][16 bl]
{
  const int bid = blockIdx.x;        // 0..63
  const int d   = bid >> 5;
  const int sl  = (bid >> 1) & 15;
  const int bh  = bid & 1;
  const int tid = threadIdx.x;
  const int kp  = tid >> 6;          // 0..7 (wave id)
  const int cg  = (tid >> 4) & 3;    // batch quad
  const int rg  = tid & 15;          // row quad
  const float* __restrict__ whh = d ? whh_b : whh_f;

  __shared__ float w_lds[256 * 64];        // w_t[k][row], row = gt*16+u   (64 KB)
  __shared__ float h_lds[256 * 20];        // h_t[k][bl(16)+pad]           (20 KB)
  __shared__ float part_lds[8 * 16 * 68];  // part[kp][bl][row(64)+pad]    (34.8 KB)

  // ---- load + transpose weight slice into LDS (once) ----
  {
    const int row_l = tid & 63;            // gt*16 + u
    const int kq    = tid >> 6;            // 0..7, 32 k each
    const int grow  = (row_l >> 4) * 256 + sl * 16 + (row_l & 15);
    const float* src = whh + (size_t)grow * H_ + kq * 32;
#pragma unroll
    for (int i = 0; i < 8; ++i) {
      f32x4 v = *(const f32x4*)(src + i * 4);
      const int kb = kq * 32 + i * 4;
      w_lds[(kb + 0) * 64 + row_l] = v.x;
      w_lds[(kb + 1) * 64 + row_l] = v.y;
      w_lds[(kb + 2) * 64 + row_l] = v.z;
      w_lds[(kb + 3) * 64 + row_l] = v.w;
    }
  }
  for (int idx = tid; idx < 256 * 20; idx += 512) h_lds[idx] = 0.f;
  __syncthreads();

  float c = 0.f;
  float* hgrp = h_all + (size_t)(d * 2 + bh) * (L_ * 256 * 16);  // [512][256][16]

  const int u_r  = tid >> 4;   // reduce-phase unit (tid<256)
  const int bl_r = tid & 15;   // reduce-phase batch
  const int kbase = kp * 32;

  // xg pointers/regs for software pipeline (tid<256 only)
  const float* xbase = xg + d * 1024 + sl * 16 + u_r;
  float xg0 = 0.f, xg1 = 0.f, xg2 = 0.f, xg3 = 0.f;
  if (tid < 256) {
    const int t0 = d ? (L_ - 1) : 0;
    const float* xp = xbase + (size_t)((bh * 16 + bl_r) * L_ + t0) * XGLD;
    xg0 = xp[0]; xg1 = xp[256]; xg2 = xp[512]; xg3 = xp[768];
  }

  for (int s = 0; s < L_; ++s) {
    const int t = d ? (L_ - 1 - s) : s;

    // ---- 4x4 register-tiled partial GEMM over this wave's 32-deep k-chunk ----
    float acc[4][4] = {};
#pragma unroll 8
    for (int i = 0; i < 32; ++i) {
      const int k = kbase + i;
      f32x4 wv = *(const f32x4*)&w_lds[k * 64 + rg * 4];
      f32x4 hv = *(const f32x4*)&h_lds[k * 20 + cg * 4];
      acc[0][0] += wv.x * hv.x; acc[0][1] += wv.x * hv.y;
      acc[0][2] += wv.x * hv.z; acc[0][3] += wv.x * hv.w;
      acc[1][0] += wv.y * hv.x; acc[1][1] += wv.y * hv.y;
      acc[1][2] += wv.y * hv.z; acc[1][3] += wv.y * hv.w;
      acc[2][0] += wv.z * hv.x; acc[2][1] += wv.z * hv.y;
      acc[2][2] += wv.z * hv.z; acc[2][3] += wv.z * hv.w;
      acc[3][0] += wv.w * hv.x; acc[3][1] += wv.w * hv.y;
      acc[3][2] += wv.w * hv.z; acc[3][3] += wv.w * hv.w;
    }
    // partials as b128: part[kp][bl = cg*4+cc][row rg*4 .. +3]
#pragma unroll
    for (int cc = 0; cc < 4; ++cc) {
      f32x4 pv = {acc[0][cc], acc[1][cc], acc[2][cc], acc[3][cc]};
      *(f32x4*)&part_lds[kp * 1088 + (cg * 4 + cc) * 68 + rg * 4] = pv;
    }
    __syncthreads();

    // ---- reduce over kp, activate, update state, publish h to LLC ----
    if (tid < 256) {
      float g0 = xg0, g1 = xg1, g2 = xg2, g3 = xg3;
#pragma unroll
      for (int k2 = 0; k2 < 8; ++k2) {
        const float* pp = &part_lds[k2 * 1088 + bl_r * 68 + u_r];
        g0 += pp[0]; g1 += pp[16]; g2 += pp[32]; g3 += pp[48];
      }
      float gi = sigmoidf_(g0);
      float gf = sigmoidf_(g1);
      float gg = tanhf(g2);
      float go = sigmoidf_(g3);
      c = gf * c + gi * gg;
      float h = go * tanhf(c);
      llc_store_f32(&hgrp[((size_t)t * 256 + sl * 16 + u_r) * 16 + bl_r], h);
    }

    if (s == L_ - 1) break;

    // issue next-step xg loads before spinning (latency hides under the spin)
    const int tn = d ? (L_ - 2 - s) : (s + 1);
    if (tid < 256) {
      const float* xp = xbase + (size_t)((bh * 16 + bl_r) * L_ + tn) * XGLD;
      xg0 = xp[0]; xg1 = xp[256]; xg2 = xp[512]; xg3 = xp[768];
    }

    // ---- spin directly on h[t] data (sentinel-filled before launch) ----
    {
      const float* hsrc = hgrp + (size_t)t * 4096;   // [256 j][16 bl]
      const int j0 = tid >> 2, bq = tid & 3;
      const float* p0 = hsrc + j0 * 16 + bq * 4;
      const float* p1 = p0 + 128 * 16;
      f32x4 v0, v1;
      bool bad;
      do {
        v0 = llc_load_f32x4(p0);
        v1 = llc_load_f32x4(p1);
        asm volatile("s_waitcnt vmcnt(0)" ::: "memory");
        __builtin_amdgcn_sched_barrier(0);
        bad = (v0.x == SENT) | (v0.y == SENT) | (v0.z == SENT) | (v0.w == SENT) |
              (v1.x == SENT) | (v1.y == SENT) | (v1.z == SENT) | (v1.w == SENT);
      } while (bad);
      *(f32x4*)&h_lds[j0 * 20 + bq * 4] = v0;
      *(f32x4*)&h_lds[(j0 + 128) * 20 + bq * 4] = v1;
    }
    __syncthreads();   // h_lds ready; also orders part_lds reuse
  }
}

// ---------- emissions: per (t, bh) tile, em[b][t][tag] = bout + h_f.Wf + h_b.Wb ------
__global__ __launch_bounds__(256) void emis_kernel(
    const float* __restrict__ h_all,  // [4][512][256][16]
    const float* __restrict__ wout,   // [4][512]
    const float* __restrict__ bout,   // [4]
    float* __restrict__ em)           // [32][512][4]
{
  __shared__ float hf_l[4096];   // [j][bl]
  __shared__ float hb_l[4096];
  __shared__ float wsl[2048];
  __shared__ float red[256];

  const int t  = blockIdx.x >> 1;
  const int bh = blockIdx.x & 1;
  const int tid = threadIdx.x;
  const float* hfp = h_all + ((size_t)(0 + bh) * L_ + t) * 4096;
  const float* hbp = h_all + ((size_t)(2 + bh) * L_ + t) * 4096;

  for (int i = tid; i < 1024; i += 256) {
    *(f32x4*)&hf_l[i * 4] = *(const f32x4*)&hfp[i * 4];
    *(f32x4*)&hb_l[i * 4] = *(const f32x4*)&hbp[i * 4];
  }
  for (int i = tid; i < 2048; i += 256) wsl[i] = wout[i];
  __syncthreads();

  const int bl = tid & 15, tag = (tid >> 4) & 3, ch = tid >> 6;
  float s = 0.f;
#pragma unroll 8
  for (int jj = 0; jj < 64; ++jj) {
    const int j = ch * 64 + jj;
    s += hf_l[j * 16 + bl] * wsl[tag * 512 + j]
       + hb_l[j * 16 + bl] * wsl[tag * 512 + 256 + j];
  }
  red[tid] = s;
  __syncthreads();
  if (tid < 64) {
    const int tg = tid >> 4, bb = tid & 15;
    float v = red[tid] + red[tid + 64] + red[tid + 128] + red[tid + 192];
    em[((size_t)(bh * 16 + bb) * L_ + t) * 4 + tg] = v + bout[tg];
  }
}

// ---------- Viterbi decode: one block per batch, em/hist staged in LDS ----------
__global__ __launch_bounds__(64) void viterbi_kernel(
    const float* __restrict__ em,      // [32][512][4]  (bias included)
    const float* __restrict__ trans,   // [4][4]
    const float* __restrict__ strans,  // [4]
    const float* __restrict__ etrans,  // [4]
    const int*   __restrict__ mask,    // [32][512]
    int* __restrict__ out)             // [32][512]
{
  __shared__ float em_l[512 * 4];
  __shared__ int   msk_l[512];
  __shared__ int   hist_l[512 * 4];
  __shared__ int   tags_l[512];

  const int b = blockIdx.x;
  const int tid = threadIdx.x;
  const float* ep = em + (size_t)b * L_ * 4;

  for (int i = tid; i < 512; i += 64) {
    *(f32x4*)&em_l[i * 4] = *(const f32x4*)&ep[i * 4];
    msk_l[i] = mask[b * L_ + i];
  }
  __syncthreads();

  if (tid == 0) {
    float tr[4][4];
#pragma unroll
    for (int i = 0; i < 4; ++i)
#pragma unroll
      for (int jj = 0; jj < 4; ++jj) tr[i][jj] = trans[i * 4 + jj];

    float sc[4];
#pragma unroll
    for (int tag = 0; tag < 4; ++tag) sc[tag] = strans[tag] + em_l[tag];

    for (int t = 1; t < L_; ++t) {
      float ns[4];
#pragma unroll
      for (int to = 0; to < 4; ++to) {
        float best = sc[0] + tr[0][to];
        int bf = 0;
#pragma unroll
        for (int fr = 1; fr < 4; ++fr) {
          float v = sc[fr] + tr[fr][to];
          if (v > best) { best = v; bf = fr; }
        }
        ns[to] = best + em_l[t * 4 + to];
        hist_l[t * 4 + to] = bf;
      }
      const int mt = msk_l[t];
#pragma unroll
      for (int to = 0; to < 4; ++to) sc[to] = mt ? ns[to] : sc[to];
    }

#pragma unroll
    for (int tag = 0; tag < 4; ++tag) sc[tag] += etrans[tag];
    int cur = 0;
    float best = sc[0];
#pragma unroll
    for (int i = 1; i < 4; ++i)
      if (sc[i] > best) { best = sc[i]; cur = i; }

    tags_l[L_ - 1] = msk_l[L_ - 1] ? cur : 0;
    for (int t = L_ - 1; t >= 1; --t) {
      if (msk_l[t]) cur = hist_l[t * 4 + cur];
      tags_l[t - 1] = msk_l[t - 1] ? cur : 0;
    }
  }
  __syncthreads();
  for (int i = tid; i < 512; i += 64) out[b * L_ + i] = tags_l[i];
}

extern "C" void kernel_launch(void* const* d_in, const int* in_sizes, int n_in,
                              void* d_out, int out_size, void* d_ws, size_t ws_size,
                              hipStream_t stream) {
  const int*   word_ids = (const int*)d_in[0];
  const int*   mask     = (const int*)d_in[1];
  // d_in[2] label_ids: unused
  const float* emb   = (const float*)d_in[3];
  const float* Wih_f = (const float*)d_in[4];
  const float* Whh_f = (const float*)d_in[5];
  const float* b_f   = (const float*)d_in[6];
  const float* Wih_b = (const float*)d_in[7];
  const float* Whh_b = (const float*)d_in[8];
  const float* b_b   = (const float*)d_in[9];
  const float* W_out = (const float*)d_in[10];
  const float* b_out = (const float*)d_in[11];
  const float* trans = (const float*)d_in[12];
  const float* strans = (const float*)d_in[13];
  const float* etrans = (const float*)d_in[14];
  int* out = (int*)d_out;

  float* xg    = (float*)d_ws;                             // 128 MiB
  float* h_all = xg + (size_t)NTOK * XGLD;                 // 4*512*4096 f32 = 32 MiB
  float* em    = h_all + (size_t)4 * L_ * 4096;            // 256 KiB

  const int n4 = 4 * L_ * 4096 / 4;                        // 2,097,152 f32x4
  fill_sentinel<<<(n4 + 255) / 256, 256, 0, stream>>>(h_all, n4);
  xproj_kernel<<<dim3(32, 256), 256, 0, stream>>>(word_ids, emb, Wih_f, Wih_b, b_f, b_b, xg);
  lstm_kernel<<<64, 512, 0, stream>>>(xg, Whh_f, Whh_b, h_all);
  emis_kernel<<<1024, 256, 0, stream>>>(h_all, W_out, b_out, em);
  viterbi_kernel<<<32, 64, 0, stream>>>(em, trans, strans, etrans, mask, out);
}